// Round 5
// baseline (265.005 us; speedup 1.0000x reference)
//
#include <hip/hip_runtime.h>
#include <math.h>

// GCN is linear: out = (((z3^T X) W1 + s2 b1) W2 + s1 b2) W3 + N b3) / sqrt(N)
// p-form propagation: p_l = dinv .* z_l ;  q_{l+1}[s] = sum_{e:src=s} p_l[dst]
//                     z_{l+1} = dinv .* (q_{l+1} + dinv .* z_l)
// so each edge pass is ONE gather + ONE atomic (no w array, no dinv gathers).
// Edge passes run 1 edge/thread (2344 blocks -> ~32 waves/CU) to maximize
// memory-level parallelism: these are latency-bound random ops.
// Multi-kernel: kernel boundaries are the cheap cross-XCD sync (coop
// grid.sync() measured 3x slower, round 3).

#define TPB 256
#define WSUM_BLOCKS 512

// deg[dst] += 1 (1 edge/thread), and zero q1..q3 (contiguous 3N) on the side
__global__ void k_deg(const int* __restrict__ dst, float* __restrict__ deg,
                      float* __restrict__ qall, int N3, int E) {
    int e = blockIdx.x * blockDim.x + threadIdx.x;
    if (e < E) atomicAdd(&deg[dst[e]], 1.0f);
    if (e < N3) qall[e] = 0.0f;   // E > 3N so one grid covers both
}

// deg (counts) -> dinv in place
__global__ void k_dinv(float* __restrict__ deg, int N) {
    int i = blockIdx.x * blockDim.x + threadIdx.x;
    if (i < N) deg[i] = (float)(1.0 / sqrt((double)deg[i] + 1.0));
}

// q[src[e]] += p[dst[e]]  — the whole edge pass
__global__ void k_q(const int* __restrict__ src, const int* __restrict__ dst,
                    const float* __restrict__ p, float* __restrict__ q, int E) {
    int e = blockIdx.x * blockDim.x + threadIdx.x;
    if (e < E) atomicAdd(&q[src[e]], p[dst[e]]);
}

// z = dinv*(q + dinv*zp) (zp==nullptr means 1) ; p = dinv*z ; *sig += sum(z)
__global__ void k_fin(const float* __restrict__ dinv, const float* __restrict__ q,
                      const float* __restrict__ zp, float* __restrict__ z,
                      float* __restrict__ p, float* __restrict__ sig, int N) {
    __shared__ float red[TPB];
    int i = blockIdx.x * blockDim.x + threadIdx.x;
    float zv = 0.0f;
    if (i < N) {
        float dv = dinv[i];
        float zprev = zp ? zp[i] : 1.0f;
        zv = dv * (q[i] + dv * zprev);
        z[i] = zv;
        p[i] = dv * zv;
    }
    red[threadIdx.x] = zv;
    __syncthreads();
    for (int s = TPB / 2; s > 0; s >>= 1) {
        if (threadIdx.x < s) red[threadIdx.x] += red[threadIdx.x + s];
        __syncthreads();
    }
    if (threadIdx.x == 0) atomicAdd(sig, red[0]);
}

// partials[b][0:128] = sum_r z3[r] * X[r][0:128], z3 = dinv*(q3 + dinv*z2)
// computed on the fly (fuses the last finish pass into the big X stream).
__global__ void k_wsum(const float* __restrict__ x, const float* __restrict__ dinv,
                       const float* __restrict__ q3, const float* __restrict__ z2,
                       float* __restrict__ partials, int N) {
    int tid = threadIdx.x;
    int c4 = (tid & 31) * 4;
    int rg = tid >> 5;
    float4 acc = make_float4(0.f, 0.f, 0.f, 0.f);
    for (int r = blockIdx.x * 8 + rg; r < N; r += gridDim.x * 8) {
        float dv = dinv[r];
        float zv = dv * (q3[r] + dv * z2[r]);
        const float4 xv = *(const float4*)(x + (size_t)r * 128 + c4);
        acc.x += zv * xv.x; acc.y += zv * xv.y;
        acc.z += zv * xv.z; acc.w += zv * xv.w;
    }
    __shared__ float4 red[TPB];
    red[tid] = acc;
    __syncthreads();
    if (tid < 32) {
        float4 a = red[tid];
        #pragma unroll
        for (int g = 1; g < 8; ++g) {
            float4 b = red[tid + 32 * g];
            a.x += b.x; a.y += b.y; a.z += b.z; a.w += b.w;
        }
        float* pp = partials + (size_t)blockIdx.x * 128 + c4;
        pp[0] = a.x; pp[1] = a.y; pp[2] = a.z; pp[3] = a.w;
    }
}

// 1024 threads: reduce partials -> u0, then 3-layer 128-wide chain with
// 8-way split-K (coalesced W reads, LDS tree reduce).
__global__ __launch_bounds__(1024) void k_final(
        const float* __restrict__ partials, int nb,
        const float* __restrict__ Ws, const float* __restrict__ bs,
        const float* __restrict__ sig, float* __restrict__ out, int N) {
    __shared__ float uv[128];
    __shared__ float red[1024];
    int t = threadIdx.x;
    int j = t & 127, g = t >> 7;            // g in [0,8)
    float acc = 0.0f;
    for (int b = g; b < nb; b += 8) acc += partials[(size_t)b * 128 + j];
    red[t] = acc;
    __syncthreads();
    if (t < 128) {
        float s = 0.0f;
        #pragma unroll
        for (int gg = 0; gg < 8; ++gg) s += red[t + 128 * gg];
        uv[t] = s;
    }
    __syncthreads();
    float s1 = sig[0], s2 = sig[1];
    for (int l = 0; l < 3; ++l) {
        const float* W = Ws + (size_t)l * 16384;
        float a = 0.0f;
        #pragma unroll
        for (int kk = 0; kk < 16; ++kk) {
            int k = g * 16 + kk;
            a += uv[k] * W[k * 128 + j];
        }
        red[t] = a;
        __syncthreads();
        float nv = 0.0f;
        if (t < 128) {
            float s = 0.0f;
            #pragma unroll
            for (int gg = 0; gg < 8; ++gg) s += red[t + 128 * gg];
            float coef = (l == 0) ? s2 : (l == 1) ? s1 : (float)N;
            nv = s + coef * bs[l * 128 + t];
        }
        __syncthreads();
        if (t < 128) uv[t] = nv;
        __syncthreads();
    }
    if (t < 128) out[t] = uv[t] * (float)(1.0 / sqrt((double)N));
}

extern "C" void kernel_launch(void* const* d_in, const int* in_sizes, int n_in,
                              void* d_out, int out_size, void* d_ws, size_t ws_size,
                              hipStream_t stream) {
    const int*   ei = (const int*)d_in[0];
    const float* X  = (const float*)d_in[1];
    const float* Ws = (const float*)d_in[2];
    const float* bs = (const float*)d_in[3];
    float* out = (float*)d_out;

    int E = in_sizes[0] / 2;
    int N = in_sizes[1] / 128;
    const int* src = ei;
    const int* dst = ei + E;

    // layout: [deg N][sig 4] (memset) [q1 q2 q3 : 3N] (zeroed by k_deg)
    //         [z1 N][z2 N][p1 N][p2 N][partials]
    float* ws       = (float*)d_ws;
    float* deg      = ws;                        // [N] -> dinv in place
    float* sig      = ws + N;                    // [4]
    float* qall     = ws + N + 4;                // [3N]
    float* q1       = qall;
    float* q2       = qall + N;
    float* q3       = qall + 2 * N;
    float* z1       = qall + 3 * N;              // [N]
    float* z2       = z1 + N;                    // [N]
    float* p1       = z2 + N;                    // [N]
    float* p2       = p1 + N;                    // [N]
    float* partials = p2 + N;                    // [WSUM_BLOCKS*128]

    hipMemsetAsync(d_ws, 0, (size_t)(N + 4) * sizeof(float), stream);

    int gE = (E + TPB - 1) / TPB;   // 1 edge per thread: max occupancy/MLP
    int gN = (N + TPB - 1) / TPB;

    k_deg  <<<gE, TPB, 0, stream>>>(dst, deg, qall, 3 * N, E);
    k_dinv <<<gN, TPB, 0, stream>>>(deg, N);
    k_q    <<<gE, TPB, 0, stream>>>(src, dst, deg, q1, E);          // q1 = A^T dinv
    k_fin  <<<gN, TPB, 0, stream>>>(deg, q1, nullptr, z1, p1, &sig[0], N);
    k_q    <<<gE, TPB, 0, stream>>>(src, dst, p1, q2, E);           // q2 = A^T p1
    k_fin  <<<gN, TPB, 0, stream>>>(deg, q2, z1, z2, p2, &sig[1], N);
    k_q    <<<gE, TPB, 0, stream>>>(src, dst, p2, q3, E);           // q3 = A^T p2
    k_wsum <<<WSUM_BLOCKS, TPB, 0, stream>>>(X, deg, q3, z2, partials, N);
    k_final<<<1, 1024, 0, stream>>>(partials, WSUM_BLOCKS, Ws, bs, sig, out, N);
}

// Round 6
// 258.190 us; speedup vs baseline: 1.0264x; 1.0264x over previous
//
#include <hip/hip_runtime.h>
#include <math.h>

// GCN is linear: out = (((z3^T X) W1 + s2 b1) W2 + s1 b2) W3 + N b3) / sqrt(N)
// p-form propagation: p_l = dinv .* z_l ;  q_{l+1}[s] = sum_{e:src=s} p_l[dst]
//                     z_{l+1} = dinv .* (q_{l+1} + dinv .* z_l)
// ROUND 6 CHANGE (single variable): all hot-path float atomics ->
// unsafeAtomicAdd (native global_atomic_add_f32, fire-and-forget) instead of
// the default CAS-loop fp32 atomicAdd; degree histogram -> native int atomics.
// Structure/dispatch count identical to round 5 for attribution.

#define TPB 256
#define WSUM_BLOCKS 512

// deg[dst] += 1 (int, native HW atomic), and zero q1..q3 (3N) on the side
__global__ void k_deg(const int* __restrict__ dst, int* __restrict__ deg,
                      float* __restrict__ qall, int N3, int E) {
    int e = blockIdx.x * blockDim.x + threadIdx.x;
    if (e < E) atomicAdd(&deg[dst[e]], 1);
    if (e < N3) qall[e] = 0.0f;   // E > 3N so one grid covers both
}

// deg (int counts) -> dinv (float) in place
__global__ void k_dinv(int* __restrict__ degi, int N) {
    int i = blockIdx.x * blockDim.x + threadIdx.x;
    if (i < N) {
        float dv = (float)(1.0 / sqrt((double)degi[i] + 1.0));
        ((float*)degi)[i] = dv;
    }
}

// q[src[e]] += p[dst[e]]  — native fp32 atomic, fire-and-forget
__global__ void k_q(const int* __restrict__ src, const int* __restrict__ dst,
                    const float* __restrict__ p, float* __restrict__ q, int E) {
    int e = blockIdx.x * blockDim.x + threadIdx.x;
    if (e < E) unsafeAtomicAdd(&q[src[e]], p[dst[e]]);
}

// z = dinv*(q + dinv*zp) (zp==nullptr means 1) ; p = dinv*z ; *sig += sum(z)
__global__ void k_fin(const float* __restrict__ dinv, const float* __restrict__ q,
                      const float* __restrict__ zp, float* __restrict__ z,
                      float* __restrict__ p, float* __restrict__ sig, int N) {
    __shared__ float red[TPB];
    int i = blockIdx.x * blockDim.x + threadIdx.x;
    float zv = 0.0f;
    if (i < N) {
        float dv = dinv[i];
        float zprev = zp ? zp[i] : 1.0f;
        zv = dv * (q[i] + dv * zprev);
        z[i] = zv;
        p[i] = dv * zv;
    }
    red[threadIdx.x] = zv;
    __syncthreads();
    for (int s = TPB / 2; s > 0; s >>= 1) {
        if (threadIdx.x < s) red[threadIdx.x] += red[threadIdx.x + s];
        __syncthreads();
    }
    if (threadIdx.x == 0) unsafeAtomicAdd(sig, red[0]);
}

// partials[b][0:128] = sum_r z3[r] * X[r][0:128], z3 = dinv*(q3 + dinv*z2)
__global__ void k_wsum(const float* __restrict__ x, const float* __restrict__ dinv,
                       const float* __restrict__ q3, const float* __restrict__ z2,
                       float* __restrict__ partials, int N) {
    int tid = threadIdx.x;
    int c4 = (tid & 31) * 4;
    int rg = tid >> 5;
    float4 acc = make_float4(0.f, 0.f, 0.f, 0.f);
    for (int r = blockIdx.x * 8 + rg; r < N; r += gridDim.x * 8) {
        float dv = dinv[r];
        float zv = dv * (q3[r] + dv * z2[r]);
        const float4 xv = *(const float4*)(x + (size_t)r * 128 + c4);
        acc.x += zv * xv.x; acc.y += zv * xv.y;
        acc.z += zv * xv.z; acc.w += zv * xv.w;
    }
    __shared__ float4 red[TPB];
    red[tid] = acc;
    __syncthreads();
    if (tid < 32) {
        float4 a = red[tid];
        #pragma unroll
        for (int g = 1; g < 8; ++g) {
            float4 b = red[tid + 32 * g];
            a.x += b.x; a.y += b.y; a.z += b.z; a.w += b.w;
        }
        float* pp = partials + (size_t)blockIdx.x * 128 + c4;
        pp[0] = a.x; pp[1] = a.y; pp[2] = a.z; pp[3] = a.w;
    }
}

// 1024 threads: reduce partials -> u0, then 3-layer 128-wide chain.
__global__ __launch_bounds__(1024) void k_final(
        const float* __restrict__ partials, int nb,
        const float* __restrict__ Ws, const float* __restrict__ bs,
        const float* __restrict__ sig, float* __restrict__ out, int N) {
    __shared__ float uv[128];
    __shared__ float red[1024];
    int t = threadIdx.x;
    int j = t & 127, g = t >> 7;            // g in [0,8)
    float acc = 0.0f;
    for (int b = g; b < nb; b += 8) acc += partials[(size_t)b * 128 + j];
    red[t] = acc;
    __syncthreads();
    if (t < 128) {
        float s = 0.0f;
        #pragma unroll
        for (int gg = 0; gg < 8; ++gg) s += red[t + 128 * gg];
        uv[t] = s;
    }
    __syncthreads();
    float s1 = sig[0], s2 = sig[1];
    for (int l = 0; l < 3; ++l) {
        const float* W = Ws + (size_t)l * 16384;
        float a = 0.0f;
        #pragma unroll
        for (int kk = 0; kk < 16; ++kk) {
            int k = g * 16 + kk;
            a += uv[k] * W[k * 128 + j];
        }
        red[t] = a;
        __syncthreads();
        float nv = 0.0f;
        if (t < 128) {
            float s = 0.0f;
            #pragma unroll
            for (int gg = 0; gg < 8; ++gg) s += red[t + 128 * gg];
            float coef = (l == 0) ? s2 : (l == 1) ? s1 : (float)N;
            nv = s + coef * bs[l * 128 + t];
        }
        __syncthreads();
        if (t < 128) uv[t] = nv;
        __syncthreads();
    }
    if (t < 128) out[t] = uv[t] * (float)(1.0 / sqrt((double)N));
}

extern "C" void kernel_launch(void* const* d_in, const int* in_sizes, int n_in,
                              void* d_out, int out_size, void* d_ws, size_t ws_size,
                              hipStream_t stream) {
    const int*   ei = (const int*)d_in[0];
    const float* X  = (const float*)d_in[1];
    const float* Ws = (const float*)d_in[2];
    const float* bs = (const float*)d_in[3];
    float* out = (float*)d_out;

    int E = in_sizes[0] / 2;
    int N = in_sizes[1] / 128;
    const int* src = ei;
    const int* dst = ei + E;

    // layout: [deg N][sig 4] (memset) [q1 q2 q3 : 3N] (zeroed by k_deg)
    //         [z1 N][z2 N][p1 N][p2 N][partials]
    float* ws       = (float*)d_ws;
    int*   deg      = (int*)ws;                  // [N] int counts -> float dinv
    float* sig      = ws + N;                    // [4]
    float* qall     = ws + N + 4;                // [3N]
    float* q1       = qall;
    float* q2       = qall + N;
    float* q3       = qall + 2 * N;
    float* z1       = qall + 3 * N;              // [N]
    float* z2       = z1 + N;                    // [N]
    float* p1       = z2 + N;                    // [N]
    float* p2       = p1 + N;                    // [N]
    float* partials = p2 + N;                    // [WSUM_BLOCKS*128]

    hipMemsetAsync(d_ws, 0, (size_t)(N + 4) * sizeof(float), stream);

    int gE = (E + TPB - 1) / TPB;
    int gN = (N + TPB - 1) / TPB;

    k_deg  <<<gE, TPB, 0, stream>>>(dst, deg, qall, 3 * N, E);
    k_dinv <<<gN, TPB, 0, stream>>>(deg, N);
    const float* dinv = (const float*)deg;
    k_q    <<<gE, TPB, 0, stream>>>(src, dst, dinv, q1, E);         // q1 = A^T dinv
    k_fin  <<<gN, TPB, 0, stream>>>(dinv, q1, nullptr, z1, p1, &sig[0], N);
    k_q    <<<gE, TPB, 0, stream>>>(src, dst, p1, q2, E);           // q2 = A^T p1
    k_fin  <<<gN, TPB, 0, stream>>>(dinv, q2, z1, z2, p2, &sig[1], N);
    k_q    <<<gE, TPB, 0, stream>>>(src, dst, p2, q3, E);           // q3 = A^T p2
    k_wsum <<<WSUM_BLOCKS, TPB, 0, stream>>>(X, dinv, q3, z2, partials, N);
    k_final<<<1, 1024, 0, stream>>>(partials, WSUM_BLOCKS, Ws, bs, sig, out, N);
}